// Round 1
// baseline (2050.836 us; speedup 1.0000x reference)
//
#include <hip/hip_runtime.h>
#include <math.h>

#define SEQ   2048
#define BATCH 128
#define HID   256
#define NCH   16   // k-chunks
#define KCH   16   // floats per chunk
#define VST   20   // chunk stride in floats (80B): 16 chunk bases -> 8 bank
                   // quads x 2 addrs = 2-way max on b128 reads (free, m136)

// dst = src's value from lane (lane perm pattern) via DPP (VALU pipe, no LDS).
// 0xB1 = quad_perm [1,0,3,2] (xor1); 0x4E = quad_perm [2,3,0,1] (xor2);
// 0x121/0x122/0x124/0x128 = row_ror:1/2/4/8 within each 16-lane row.
// ror8 == xor8 within 16 lanes; ror4 == xor4 HERE because after the ror8
// fold lanes l and l^8 are bitwise duplicates (lane l+4's rotate source
// l+8.. is the dup of the true xor partner l^4).
template <int CTRL>
__device__ __forceinline__ float dpp_mov(float x) {
    return __int_as_float(__builtin_amdgcn_update_dpp(
        __float_as_int(x), __float_as_int(x), CTRL, 0xF, 0xF, false));
}

// Workgroup barrier draining ONLY lgkmcnt. __syncthreads() emits
// s_waitcnt vmcnt(0) lgkmcnt(0) before s_barrier (guide §5), which makes
// every step pay the global h-store ack latency (~300-500 cyc) for a store
// nothing in-kernel reads. LDS double-buffer correctness needs only lgkm:
// each wave's ds_reads of buffer X are lgkm-drained before it reaches the
// barrier, so X may be rewritten one step later race-free.
// sched_barrier(0) pins memory ops around the inline asm (rule #18).
__device__ __forceinline__ void lds_barrier() {
    asm volatile("s_waitcnt lgkmcnt(0)" ::: "memory");
    __builtin_amdgcn_sched_barrier(0);
    __builtin_amdgcn_s_barrier();
    __builtin_amdgcn_sched_barrier(0);
}

// One block (512 threads, 8 waves, 2 waves/SIMD) per batch element. fp32.
// Thread (R=tid>>4, l=tid&15): k-chunk [16l,16l+16), rows 8R+((tid&7)^j),
// j=0..7 -> 128 weight fp32 in VGPRs. Reduce is now DPP-only: fold l<->l^8
// (ror8), xor1/xor2 via quad_perm, final xor4 via ror4 (dup-trick above).
// Threads tid and tid^8 duplicate the same row bitwise-identically.
// v = 2h-1 fp32, double-buffered, ONE lgkm-only barrier/step.
// y head is FUSED: p = h*W0[row]; rotate-reduce (ror4,ror2,ror1) leaves each
// 16-group's 8-row partial at its lane0 -> 32 partials/step in LDS (dbuf);
// wave ((t-1)&7) sums them NEXT step (broadcast b128 reads overlap the
// v-fragment load latency) and stores y[t-1]. No head kernel, no workspace.
__global__ __launch_bounds__(512) __attribute__((amdgpu_waves_per_eu(2, 2)))
void rnn_scan_kernel(const float* __restrict__ x,        // (SEQ, BATCH)
                     const float* __restrict__ h0,       // (BATCH, HID)
                     const float* __restrict__ W_ih,     // (HID, 1)
                     const float* __restrict__ W_hh,     // (HID, HID)
                     const float* __restrict__ W_hh_b,   // (HID, HID)
                     const float* __restrict__ b_h,      // (HID,)
                     const int*   __restrict__ context,  // scalar
                     const float* __restrict__ Wout,     // (OUT, HID), row 0
                     const float* __restrict__ bias,     // (OUT,), [0]
                     float*       __restrict__ out_hs,   // (BATCH, SEQ, HID)
                     float*       __restrict__ out_y)    // (BATCH, SEQ)
{
    const int b   = blockIdx.x;
    const int tid = threadIdx.x;
    const int R   = tid >> 4;    // row-group: rows [8R, 8R+8)
    const int l   = tid & 15;    // k-chunk index
    const int l7  = tid & 7;
    const int row = 8 * R + l7;  // row this thread owns after the reduce
    const int w   = tid >> 6;    // wave id 0..7

    __shared__ __align__(16) float v_lds[2][NCH * VST];
    __shared__ float x_lds[SEQ];
    __shared__ __align__(16) float ypart[2][32];  // per-16-group y partials

    for (int t = tid; t < SEQ; t += 512)
        x_lds[t] = x[t * BATCH + b];

    const float ctx = (float)context[0];

    // wreg[j][c] = W_eff[8R + (l7^j)][16l + 4c .. +3]  (XOR-ordered rows)
    float4 wreg[8][4];
    #pragma unroll
    for (int j = 0; j < 8; ++j) {
        const int rj = 8 * R + (l7 ^ j);
        const float* wp = W_hh   + (size_t)rj * HID + KCH * l;
        const float* bp = W_hh_b + (size_t)rj * HID + KCH * l;
        #pragma unroll
        for (int c = 0; c < 4; ++c) {
            const float4 a = *(const float4*)(wp + 4 * c);
            const float4 d = *(const float4*)(bp + 4 * c);
            wreg[j][c] = make_float4(a.x + ctx * d.x, a.y + ctx * d.y,
                                     a.z + ctx * d.z, a.w + ctx * d.w);
        }
    }

    const float winj = W_ih[row];
    const float bhj  = b_h[row];
    const float w0   = Wout[row];   // W[0, row]
    const float b0   = bias[0];

    const int voff = VST * (row >> 4) + (row & 15);
    v_lds[0][voff] = 2.f * h0[(size_t)b * HID + row] - 1.f;  // dup-safe

    float* outp = out_hs + (size_t)b * SEQ * HID + row;
    float* yp   = out_y  + (size_t)b * SEQ;

    const float4* vr0 = (const float4*)(v_lds[0] + VST * l);  // 80B-stride
    const float4* vr1 = (const float4*)(v_lds[1] + VST * l);

    lds_barrier();  // v[0] + x_lds ready

    auto step = [&](int t, const float4* __restrict__ vr,
                    float* __restrict__ vw, int pb) {
        // Finalize y[t-1] from last step's partials on one wave; broadcast
        // b128 reads overlap this step's v-fragment load latency.
        const int prev = t - 1;
        if (prev >= 0 && w == (prev & 7)) {
            const float4* pp = (const float4*)(ypart[pb ^ 1]);
            float s = 0.f;
            #pragma unroll
            for (int u = 0; u < 8; ++u) {
                const float4 a = pp[u];
                s += (a.x + a.y) + (a.z + a.w);
            }
            if ((tid & 63) == 0) yp[prev] = s + b0;
        }

        float q[8] = {0.f, 0.f, 0.f, 0.f, 0.f, 0.f, 0.f, 0.f};
        #pragma unroll
        for (int c = 0; c < 4; ++c) {
            const float4 v4 = vr[c];
            #pragma unroll
            for (int j = 0; j < 8; ++j) {
                const float4 wv = wreg[j][c];
                q[j] += wv.x * v4.x;
                q[j] += wv.y * v4.y;
                q[j] += wv.z * v4.z;
                q[j] += wv.w * v4.w;
            }
        }
        // Fold l <-> l^8: same rows, complementary k-halves (establishes
        // the lane<->lane^8 duplicate structure).
        #pragma unroll
        for (int j = 0; j < 8; ++j) q[j] += dpp_mov<0x128>(q[j]);
        // XOR transpose-reduce, all-DPP (quad_perm xor1/xor2 preserve the
        // +-8 dup, so the final xor4 is a plain ror4).
        q[0] += dpp_mov<0xB1>(q[1]);
        q[2] += dpp_mov<0xB1>(q[3]);
        q[4] += dpp_mov<0xB1>(q[5]);
        q[6] += dpp_mov<0xB1>(q[7]);
        q[0] += dpp_mov<0x4E>(q[2]);
        q[4] += dpp_mov<0x4E>(q[6]);
        q[0] += dpp_mov<0x124>(q[4]);
        // q[0] = full dot for row 8R + l7 (dup in tid and tid^8)

        const float pre = q[0] + bhj + x_lds[t] * winj;
        const float h = 1.f / (1.f + __expf(-pre));
        vw[voff] = 2.f * h - 1.f;                 // dup write, same value
        if ((tid & 8) == 0)
            outp[(size_t)t * HID] = h;            // 32 lanes/wave, contiguous

        // y partial: rotate-reduce 8 distinct rows of this 16-lane group
        // (lanes 8..15 are duplicates; lane0 sums each row exactly once).
        float p = h * w0;
        p += dpp_mov<0x124>(p);   // +ror4
        p += dpp_mov<0x122>(p);   // +ror2
        p += dpp_mov<0x121>(p);   // +ror1 -> lane0: sum of rows 8R..8R+7
        if ((tid & 15) == 0) ypart[pb][tid >> 4] = p;

        lds_barrier();  // v for t+1 + partials ready; buffers fully read
    };

    for (int t = 0; t < SEQ; t += 2) {
        step(t,     vr0, v_lds[1], 0);
        step(t + 1, vr1, v_lds[0], 1);
    }

    // Finalize y[SEQ-1] (last step wrote ypart[1]; loop's trailing barrier
    // made it visible).
    if (w == ((SEQ - 1) & 7)) {
        const float4* pp = (const float4*)(ypart[1]);
        float s = 0.f;
        #pragma unroll
        for (int u = 0; u < 8; ++u) {
            const float4 a = pp[u];
            s += (a.x + a.y) + (a.z + a.w);
        }
        if ((tid & 63) == 0) yp[SEQ - 1] = s + b0;
    }
}

extern "C" void kernel_launch(void* const* d_in, const int* in_sizes, int n_in,
                              void* d_out, int out_size, void* d_ws, size_t ws_size,
                              hipStream_t stream) {
    const float* x      = (const float*)d_in[0];
    const float* h0     = (const float*)d_in[1];
    const float* W_ih   = (const float*)d_in[2];
    const float* W_hh   = (const float*)d_in[3];
    const float* W_hh_b = (const float*)d_in[4];
    const float* b_h    = (const float*)d_in[5];
    const float* W      = (const float*)d_in[6];
    const float* bias   = (const float*)d_in[7];
    const int*   ctx    = (const int*)d_in[8];

    float* y  = (float*)d_out;                // (BATCH*SEQ,) = y[:,:,0]
    float* hs = y + (size_t)BATCH * SEQ;      // (BATCH, SEQ, HID) = out

    rnn_scan_kernel<<<BATCH, 512, 0, stream>>>(x, h0, W_ih, W_hh, W_hh_b,
                                               b_h, ctx, W, bias, hs, y);
}